// Round 4
// baseline (455.661 us; speedup 1.0000x reference)
//
#include <hip/hip_runtime.h>

// Conv2d: data [32,1,224,224] f32, weight [64,1,3,3] f32 -> out [32,64,222,222] f32
// VALID, stride 1, cross-correlation. Write-BW bound (403.7 MB out).
//
// R1-R4 ledger:
//   R1 436us: channel pair in grid.y, row-structured float2 stores.
//   R2 533us: CPT=8 + 8B NONTEMPORAL stores. nt bypassed L2 write-combining
//     -> partial-line HBM writes. nt convicted, CPT=8 was confounded.
//   R3 427us: flat-per-plane float4 stores (perfect micro-structure): only -2%.
//     Store ALIGNMENT/count exonerated.
//   R4 411us: CPT=8 cached: -16us. Reads mostly exonerated (input of batch b is
//     consumed within a ~5us dispatch window; ~6.4MB HBM reads total).
//   Conv is ~146us for 404MB = 2.8 TB/s vs fill's 6.1 TB/s on the SAME HW.
// R5 theory: the fill advances ONE contiguous write front (grid-stride,
//   consecutive threads -> consecutive addresses). Our conv had ~16K distinct
//   1KB plane-strided write fronts over a 64MB window -> HBM row-activate
//   thrash halves write BW. Fix: flat grid-stride over the WHOLE output
//   [b][ch][plane] in float4 units -> single dense ~4MB advancing front.
//   Weights become per-lane loads but are wave-uniform except at plane-straddle
//   waves (~0.5%) -> L1 broadcast. Decode = 2 magic-mul divides/iter.

#define IN_H 224
#define IN_W 224
#define OUT_H 222
#define OUT_W 222
#define OUT_C 64
#define BATCH 32
#define PLANE (OUT_H * OUT_W)      // 49284 floats = 197136 B (16B-mult size)
#define G4 (PLANE / 4)             // 12321 float4 groups per plane
#define NPLANES (BATCH * OUT_C)    // 2048
#define TOTAL4 ((unsigned)NPLANES * G4)  // 25,233,408 float4 outputs

#define NBLOCKS 1024
#define NTHREADS 256

typedef float v4f __attribute__((ext_vector_type(4)));
struct __attribute__((aligned(8))) v4u8 { v4f v; };   // 8B-aligned float4 view

__global__ __launch_bounds__(NTHREADS) void conv3x3_kernel(
    const float* __restrict__ in, const float* __restrict__ wt,
    float* __restrict__ out) {
  const unsigned stride = NBLOCKS * NTHREADS;
  for (unsigned i = blockIdx.x * NTHREADS + threadIdx.x; i < TOTAL4; i += stride) {
    const unsigned plane = i / (unsigned)G4;       // magic-mul
    const unsigned rem   = i - plane * (unsigned)G4;
    const unsigned b     = plane >> 6;             // plane = b*64 + ch
    const unsigned ch    = plane & 63u;

    const unsigned f0 = rem * 4u;                  // flat idx within plane
    const unsigned fB = f0 + 2u;
    const unsigned yA = f0 / 222u;                 // magic-mul
    const unsigned xA = f0 - yA * 222u;            // even, 0..220
    const unsigned yB = fB / 222u;
    const unsigned xB = fB - yB * 222u;            // even, 0..220

    // Input windows rows y..y+2, cols x..x+3 (max col 223, in range).
    // 8B-aligned addresses (all index terms even).
    const float* ibase = in + (size_t)b * (IN_H * IN_W);
    const float* pA = ibase + yA * IN_W + xA;
    const float* pB = ibase + yB * IN_W + xB;
    const v4f A0 = ((const v4u8*)(pA))->v;
    const v4f A1 = ((const v4u8*)(pA + IN_W))->v;
    const v4f A2 = ((const v4u8*)(pA + 2 * IN_W))->v;
    const v4f B0 = ((const v4u8*)(pB))->v;
    const v4f B1 = ((const v4u8*)(pB + IN_W))->v;
    const v4f B2 = ((const v4u8*)(pB + 2 * IN_W))->v;

    // Weights: wave-uniform address except at plane-straddle waves -> L1
    // broadcast loads. 9 dwords.
    const float* w = wt + ch * 9;
    const float w00 = w[0], w01 = w[1], w02 = w[2];
    const float w10 = w[3], w11 = w[4], w12 = w[5];
    const float w20 = w[6], w21 = w[7], w22 = w[8];

    float o0, o1, o2, o3;
    o0 = fmaf(A0.x, w00, fmaf(A0.y, w01, A0.z * w02));
    o0 = fmaf(A1.x, w10, fmaf(A1.y, w11, fmaf(A1.z, w12, o0)));
    o0 = fmaf(A2.x, w20, fmaf(A2.y, w21, fmaf(A2.z, w22, o0)));

    o1 = fmaf(A0.y, w00, fmaf(A0.z, w01, A0.w * w02));
    o1 = fmaf(A1.y, w10, fmaf(A1.z, w11, fmaf(A1.w, w12, o1)));
    o1 = fmaf(A2.y, w20, fmaf(A2.z, w21, fmaf(A2.w, w22, o1)));

    o2 = fmaf(B0.x, w00, fmaf(B0.y, w01, B0.z * w02));
    o2 = fmaf(B1.x, w10, fmaf(B1.y, w11, fmaf(B1.z, w12, o2)));
    o2 = fmaf(B2.x, w20, fmaf(B2.y, w21, fmaf(B2.z, w22, o2)));

    o3 = fmaf(B0.y, w00, fmaf(B0.z, w01, B0.w * w02));
    o3 = fmaf(B1.y, w10, fmaf(B1.z, w11, fmaf(B1.w, w12, o3)));
    o3 = fmaf(B2.y, w20, fmaf(B2.z, w21, fmaf(B2.w, w22, o3)));

    v4f o = {o0, o1, o2, o3};
    // Consecutive threads -> consecutive 16B-aligned stores across the whole
    // grid: one dense advancing write front (the fill's topology).
    *(v4f*)(out + (size_t)plane * PLANE + f0) = o;
  }
}

extern "C" void kernel_launch(void* const* d_in, const int* in_sizes, int n_in,
                              void* d_out, int out_size, void* d_ws, size_t ws_size,
                              hipStream_t stream) {
  const float* data   = (const float*)d_in[0];
  const float* weight = (const float*)d_in[1];
  float* out = (float*)d_out;

  conv3x3_kernel<<<dim3(NBLOCKS), dim3(NTHREADS), 0, stream>>>(data, weight, out);
}

// Round 7
// 420.132 us; speedup vs baseline: 1.0846x; 1.0846x over previous
//
#include <hip/hip_runtime.h>

// Conv2d: data [32,1,224,224] f32, weight [64,1,3,3] f32 -> out [32,64,222,222] f32
// VALID, stride 1, cross-correlation. Write-BW bound (403.7 MB out).
//
// Ledger:
//   R1 436us: ch-pair grid.y, float2 stores.
//   R2 533us: CPT=8 + 8B nontemporal. nt-on-partial-lines convicted.
//   R3 427us: flat-plane float4 stores. Store micro-structure exonerated.
//   R4 411us (best): CPT=8 cached f4. conv ~146us = 2.8 TB/s vs fill 6.1 TB/s.
//   R5 456us: flat grid-stride single-front — confounded: lost CPT-8 reuse
//     (8x L1 read traffic, per-lane weight loads). Front theory NOT refuted.
//   R6/R7: container infra failure x2 on the persistent-block source — no
//     data. Resubmitting with defensive simplifications: NBLK=448 (exactly 28
//     chunks/block, integer trip count), no `continue`, flattened decode.
// Theory under test: fill's 6.1 TB/s comes from ONE dense write front (DRAM
//   page hits); R4 keeps ~330 plane-fronts live (2048 in-flight blocks / 392
//   blocks-per-batch = 5.2 batches x 64 planes) -> row-activate thrash halves
//   write BW. Fix, holding R4's read structure constant: 448 persistent
//   blocks walk chunks batch-major -> live window ~1.1 batches (~73 planes).
//   Per-thread body identical to R4: 96B input window -> 8 channels x 1
//   float4, SGPR weights, cached 16B stores.

#define IN_H 224
#define IN_W 224
#define OUT_H 222
#define OUT_W 222
#define OUT_C 64
#define BATCH 32
#define PLANE (OUT_H * OUT_W)        // 49284 floats = 197136 B
#define G4 (PLANE / 4)               // 12321 float4 groups per plane
#define CPT 8                        // channels per thread
#define CHUNKS_PER_PLANE 49          // ceil(G4 / 256)
#define CHUNKS_PER_BATCH (CHUNKS_PER_PLANE * (OUT_C / CPT))   // 392
#define TOTAL_CHUNKS (CHUNKS_PER_BATCH * BATCH)               // 12544
#define NBLK 448                     // 12544 / 448 = 28 chunks per block, exact

typedef float v4f __attribute__((ext_vector_type(4)));
struct __attribute__((aligned(8))) v4u8 { v4f v; };   // 8B-aligned float4 view

__global__ __launch_bounds__(256) void conv3x3_kernel(
    const float* __restrict__ in, const float* __restrict__ wt,
    float* __restrict__ out) {
  #pragma unroll 1
  for (int it = 0; it < TOTAL_CHUNKS / NBLK; ++it) {
    const unsigned chunk = (unsigned)it * NBLK + blockIdx.x;  // batch-major walk

    // Decode chunk -> (batch, channel-group, chunk-in-plane). Uniform per
    // block -> scalar ops.
    const unsigned b   = chunk / CHUNKS_PER_BATCH;
    const unsigned r   = chunk - b * CHUNKS_PER_BATCH;
    const unsigned cg  = r / CHUNKS_PER_PLANE;           // channel group 0..7
    const unsigned cx  = r - cg * CHUNKS_PER_PLANE;      // chunk in plane 0..48
    const unsigned ch0 = cg * CPT;

    const unsigned t = cx * 256u + threadIdx.x;          // float4 group in plane
    if (t < G4) {                                        // tail chunk guard
      const unsigned f0 = t * 4u;                        // flat idx within plane
      const unsigned fB = f0 + 2u;
      const unsigned yA = f0 / 222u;                     // magic-mul
      const unsigned xA = f0 - yA * 222u;                // even, 0..220
      const unsigned yB = fB / 222u;
      const unsigned xB = fB - yB * 222u;                // even, 0..220

      // Input windows rows y..y+2, cols x..x+3 (max col 223, in range).
      // 8B-aligned addresses (all index terms even).
      const float* ibase = in + (size_t)b * (IN_H * IN_W);
      const float* pA = ibase + yA * IN_W + xA;
      const float* pB = ibase + yB * IN_W + xB;
      const v4f A0 = ((const v4u8*)(pA))->v;
      const v4f A1 = ((const v4u8*)(pA + IN_W))->v;
      const v4f A2 = ((const v4u8*)(pA + 2 * IN_W))->v;
      const v4f B0 = ((const v4u8*)(pB))->v;
      const v4f B1 = ((const v4u8*)(pB + IN_W))->v;
      const v4f B2 = ((const v4u8*)(pB + 2 * IN_W))->v;

      float* op = out + (size_t)(b * OUT_C + ch0) * PLANE + f0;  // 16B-aligned

      #pragma unroll
      for (int c = 0; c < CPT; ++c) {
        const float* w = wt + (ch0 + c) * 9;   // uniform -> s_load into SGPRs
        const float w00 = w[0], w01 = w[1], w02 = w[2];
        const float w10 = w[3], w11 = w[4], w12 = w[5];
        const float w20 = w[6], w21 = w[7], w22 = w[8];

        float o0, o1, o2, o3;
        o0 = fmaf(A0.x, w00, fmaf(A0.y, w01, A0.z * w02));
        o0 = fmaf(A1.x, w10, fmaf(A1.y, w11, fmaf(A1.z, w12, o0)));
        o0 = fmaf(A2.x, w20, fmaf(A2.y, w21, fmaf(A2.z, w22, o0)));

        o1 = fmaf(A0.y, w00, fmaf(A0.z, w01, A0.w * w02));
        o1 = fmaf(A1.y, w10, fmaf(A1.z, w11, fmaf(A1.w, w12, o1)));
        o1 = fmaf(A2.y, w20, fmaf(A2.z, w21, fmaf(A2.w, w22, o1)));

        o2 = fmaf(B0.x, w00, fmaf(B0.y, w01, B0.z * w02));
        o2 = fmaf(B1.x, w10, fmaf(B1.y, w11, fmaf(B1.z, w12, o2)));
        o2 = fmaf(B2.x, w20, fmaf(B2.y, w21, fmaf(B2.z, w22, o2)));

        o3 = fmaf(B0.y, w00, fmaf(B0.z, w01, B0.w * w02));
        o3 = fmaf(B1.y, w10, fmaf(B1.z, w11, fmaf(B1.w, w12, o3)));
        o3 = fmaf(B2.y, w20, fmaf(B2.z, w21, fmaf(B2.w, w22, o3)));

        v4f o = {o0, o1, o2, o3};
        *(v4f*)op = o;                         // single 16B-aligned cached store
        op += PLANE;
      }
    }
  }
}

extern "C" void kernel_launch(void* const* d_in, const int* in_sizes, int n_in,
                              void* d_out, int out_size, void* d_ws, size_t ws_size,
                              hipStream_t stream) {
  const float* data   = (const float*)d_in[0];
  const float* weight = (const float*)d_in[1];
  float* out = (float*)d_out;

  conv3x3_kernel<<<dim3(NBLK), dim3(256), 0, stream>>>(data, weight, out);
}

// Round 8
// 418.104 us; speedup vs baseline: 1.0898x; 1.0049x over previous
//
#include <hip/hip_runtime.h>

// Conv2d: data [32,1,224,224] f32, weight [64,1,3,3] f32 -> out [32,64,222,222] f32
// VALID, stride 1, cross-correlation. Write-BW bound (403.7 MB out).
//
// Ledger:
//   R1 436us: ch-pair grid.y, float2 stores.
//   R2 533us: CPT=8 + 8B nontemporal. Partial-line nt stores defeat write
//     combining -> convicted (granularity, not nt itself).
//   R3 427us: flat-plane float4 stores. Store micro-structure exonerated.
//   R4 411us (BEST): CPT=8 cached f4. conv ~146us = 2.8 TB/s vs fill 6.1 TB/s.
//   R5 456us: flat grid-stride single-front — confounded (lost CPT-8 reuse).
//   R7 420us: 448 persistent blocks, batch-major (live window ~73 planes):
//     conv ~154us. WRITE-FRONT TOPOLOGY THEORY DEAD — 3 topology experiments
//     (R3/R5/R7) all failed to move write BW.
// R8 theory: topology at ISSUE time doesn't matter because cached stores
//   write-allocate in the 4MB/XCD L2; pushing 404MB through 32MB of L2 means
//   HBM receives lines in victim-EVICTION order (set-scrambled), killing DRAM
//   page locality regardless of issue order. fillBuffer's 6.1 TB/s comes from
//   streaming stores that bypass L2. Fix: R4 unchanged except stores are
//   __builtin_nontemporal_store of float4 (full 16B/lane, wave-contiguous 1KB
//   runs, 4KB dense per block-channel -> clean write-combining, unlike R2's
//   8B granules). Single-variable vs R4.

#define IN_H 224
#define IN_W 224
#define OUT_H 222
#define OUT_W 222
#define OUT_C 64
#define BATCH 32
#define PLANE (OUT_H * OUT_W)      // 49284 floats = 197136 B (16B-mult size)
#define G4 (PLANE / 4)             // 12321 float4 groups per plane
#define CPT 8                      // channels per thread

typedef float v4f __attribute__((ext_vector_type(4)));
struct __attribute__((aligned(8))) v4u8 { v4f v; };   // 8B-aligned float4 view

__global__ __launch_bounds__(256) void conv3x3_kernel(
    const float* __restrict__ in, const float* __restrict__ wt,
    float* __restrict__ out) {
  const unsigned tid = blockIdx.x * blockDim.x + threadIdx.x;  // float4 group in plane
  if (tid >= G4) return;
  const int b   = blockIdx.z;
  const int ch0 = blockIdx.y * CPT;          // wave-uniform channel group

  const unsigned f0 = tid * 4u;              // flat output index in plane
  const unsigned fB = f0 + 2u;
  const unsigned yA = f0 / 222u;             // magic-mul division
  const unsigned xA = f0 - yA * 222u;        // even, 0..220
  const unsigned yB = fB / 222u;
  const unsigned xB = fB - yB * 222u;        // even, 0..220

  // Input windows: rows y..y+2, cols x..x+3 (x<=220 -> max col 223, in range).
  // Byte addresses are 8B-aligned (all index terms even).
  const float* ibase = in + (size_t)b * (IN_H * IN_W);
  const float* pA = ibase + yA * IN_W + xA;
  const float* pB = ibase + yB * IN_W + xB;
  const v4f A0 = ((const v4u8*)(pA))->v;
  const v4f A1 = ((const v4u8*)(pA + IN_W))->v;
  const v4f A2 = ((const v4u8*)(pA + 2 * IN_W))->v;
  const v4f B0 = ((const v4u8*)(pB))->v;
  const v4f B1 = ((const v4u8*)(pB + IN_W))->v;
  const v4f B2 = ((const v4u8*)(pB + 2 * IN_W))->v;

  float* op = out + (size_t)(b * OUT_C + ch0) * PLANE + f0;  // 16B-aligned

  #pragma unroll
  for (int c = 0; c < CPT; ++c) {
    const float* w = wt + (ch0 + c) * 9;     // uniform -> s_load into SGPRs
    const float w00 = w[0], w01 = w[1], w02 = w[2];
    const float w10 = w[3], w11 = w[4], w12 = w[5];
    const float w20 = w[6], w21 = w[7], w22 = w[8];

    float o0, o1, o2, o3;
    o0 = fmaf(A0.x, w00, fmaf(A0.y, w01, A0.z * w02));
    o0 = fmaf(A1.x, w10, fmaf(A1.y, w11, fmaf(A1.z, w12, o0)));
    o0 = fmaf(A2.x, w20, fmaf(A2.y, w21, fmaf(A2.z, w22, o0)));

    o1 = fmaf(A0.y, w00, fmaf(A0.z, w01, A0.w * w02));
    o1 = fmaf(A1.y, w10, fmaf(A1.z, w11, fmaf(A1.w, w12, o1)));
    o1 = fmaf(A2.y, w20, fmaf(A2.z, w21, fmaf(A2.w, w22, o1)));

    o2 = fmaf(B0.x, w00, fmaf(B0.y, w01, B0.z * w02));
    o2 = fmaf(B1.x, w10, fmaf(B1.y, w11, fmaf(B1.z, w12, o2)));
    o2 = fmaf(B2.x, w20, fmaf(B2.y, w21, fmaf(B2.z, w22, o2)));

    o3 = fmaf(B0.y, w00, fmaf(B0.z, w01, B0.w * w02));
    o3 = fmaf(B1.y, w10, fmaf(B1.z, w11, fmaf(B1.w, w12, o3)));
    o3 = fmaf(B2.y, w20, fmaf(B2.z, w21, fmaf(B2.w, w22, o3)));

    v4f o = {o0, o1, o2, o3};
    // Streaming store: full 16B/lane, wave-contiguous -> full-line write
    // combining; bypasses L2 allocation so HBM sees issue-order dense runs
    // (the fill's behavior) instead of eviction-order scramble.
    __builtin_nontemporal_store(o, (v4f*)op);
    op += PLANE;
  }
}

extern "C" void kernel_launch(void* const* d_in, const int* in_sizes, int n_in,
                              void* d_out, int out_size, void* d_ws, size_t ws_size,
                              hipStream_t stream) {
  const float* data   = (const float*)d_in[0];
  const float* weight = (const float*)d_in[1];
  float* out = (float*)d_out;

  dim3 grid((G4 + 255) / 256, OUT_C / CPT, BATCH);
  conv3x3_kernel<<<grid, 256, 0, stream>>>(data, weight, out);
}